// Round 1
// baseline (575.515 us; speedup 1.0000x reference)
//
#include <hip/hip_runtime.h>
#include <math.h>

typedef short short8 __attribute__((ext_vector_type(8)));
typedef float f32x4 __attribute__((ext_vector_type(4)));

#define B_ 16
#define TQ_ 64
#define TK_ 512
#define D_ 256
#define V_ 32000
#define M_ (B_ * TQ_)   // 1024 rows

__device__ __forceinline__ unsigned short f2bf(float x) {
    unsigned int u = __float_as_uint(x);
    unsigned int r = (u + 0x7fffu + ((u >> 16) & 1u)) >> 16;
    return (unsigned short)r;
}

// ---------------- dedup: per-batch leader/next chains over context_plain ----------------
__global__ __launch_bounds__(256) void dedup_kernel(
    const int* __restrict__ cp, int* __restrict__ nexta, int* __restrict__ leader)
{
    __shared__ int c[TK_];
    const int b = blockIdx.x, tid = threadIdx.x;
    c[tid] = cp[b * TK_ + tid];
    c[tid + 256] = cp[b * TK_ + 256 + tid];
    __syncthreads();
    for (int k = tid; k < TK_; k += 256) {
        const int v = c[k];
        int ld = 1, nx = -1;
        for (int j = 0; j < k; j++) if (c[j] == v) { ld = 0; break; }
        for (int j = k + 1; j < TK_; j++) if (c[j] == v) { nx = j; break; }
        nexta[b * TK_ + k] = nx;
        leader[b * TK_ + k] = ld;
    }
}

// ---------------- convert out_states f32 -> bf16 (row-major [1024][256]) ----------------
__global__ __launch_bounds__(256) void conv_a_kernel(
    const float* __restrict__ A, unsigned short* __restrict__ Ab)
{
    const int i = (blockIdx.x * 256 + threadIdx.x) * 4;
    const float4 v = *(const float4*)&A[i];
    ushort4 o;
    o.x = f2bf(v.x); o.y = f2bf(v.y); o.z = f2bf(v.z); o.w = f2bf(v.w);
    *(ushort4*)&Ab[i] = o;
}

// ---------------- convert + transpose W_state [256][32000] f32 -> Wt [32000][256] bf16 ----
__global__ __launch_bounds__(256) void conv_w_kernel(
    const float* __restrict__ W, unsigned short* __restrict__ Wt)
{
    __shared__ float tile[64][65];
    const int tid = threadIdx.x;
    const int k0 = (blockIdx.x & 3) * 64;
    const int n0 = (blockIdx.x >> 2) * 64;
#pragma unroll
    for (int i = 0; i < 16; i++) {
        const int r = i * 4 + (tid >> 6), cc = tid & 63;
        tile[r][cc] = W[(k0 + r) * V_ + n0 + cc];
    }
    __syncthreads();
#pragma unroll
    for (int i = 0; i < 4; i++) {
        const int nl = i * 16 + (tid >> 4);
        const int kq = (tid & 15) * 4;
        ushort4 o;
        o.x = f2bf(tile[kq + 0][nl]);
        o.y = f2bf(tile[kq + 1][nl]);
        o.z = f2bf(tile[kq + 2][nl]);
        o.w = f2bf(tile[kq + 3][nl]);
        *(ushort4*)&Wt[(n0 + nl) * D_ + k0 + kq] = o;
    }
}

// ---------------- stage A: scores -> softmax -> context_vec -> p_gen; QG=4 rows/block ----
__global__ __launch_bounds__(256) void stage_a_kernel(
    const float* __restrict__ out_states, const float* __restrict__ context,
    const float* __restrict__ domainslots, const float* __restrict__ W_gen,
    const float* __restrict__ b_gen, float* __restrict__ attn_out,
    float* __restrict__ pg_out)
{
    __shared__ float qv[4][D_];
    __shared__ float at[4][TK_];
    __shared__ float red[4][4];   // [wave][qi]
    const int tid = threadIdx.x;
    const int b = blockIdx.x >> 4;
    const int q0 = (blockIdx.x & 15) * 4;
#pragma unroll
    for (int qi = 0; qi < 4; qi++)
        qv[qi][tid] = out_states[((b * TQ_) + q0 + qi) * D_ + tid];
    __syncthreads();
    const int w = tid >> 6, lane = tid & 63;
    // scores: wave handles k = w mod 4; lanes cover D via float4; shfl-reduce
    for (int k = w; k < TK_; k += 4) {
        const float4 c4 = *(const float4*)&context[((b * TK_) + k) * D_ + lane * 4];
#pragma unroll
        for (int qi = 0; qi < 4; qi++) {
            const float4 q4 = *(const float4*)&qv[qi][lane * 4];
            float s = c4.x * q4.x + c4.y * q4.y + c4.z * q4.z + c4.w * q4.w;
#pragma unroll
            for (int off = 32; off; off >>= 1) s += __shfl_xor(s, off);
            if (lane == 0) at[qi][k] = s * 0.0625f;   // / sqrt(256)
        }
    }
    __syncthreads();
    // softmax over TK: wave w owns qi=w
    {
        const int qi = w;
        float v[8], m = -1e30f;
#pragma unroll
        for (int j = 0; j < 8; j++) { v[j] = at[qi][lane + 64 * j]; m = fmaxf(m, v[j]); }
#pragma unroll
        for (int off = 32; off; off >>= 1) m = fmaxf(m, __shfl_xor(m, off));
        float s = 0.f;
#pragma unroll
        for (int j = 0; j < 8; j++) { v[j] = __expf(v[j] - m); s += v[j]; }
#pragma unroll
        for (int off = 32; off; off >>= 1) s += __shfl_xor(s, off);
        const float inv = 1.0f / s;
#pragma unroll
        for (int j = 0; j < 8; j++) at[qi][lane + 64 * j] = v[j] * inv;
    }
    __syncthreads();
    // context_vec (each thread owns dim d=tid) + p_gen partial
    float cv[4] = {0.f, 0.f, 0.f, 0.f};
    for (int k = 0; k < TK_; k++) {
        const float c = context[((b * TK_) + k) * D_ + tid];
#pragma unroll
        for (int qi = 0; qi < 4; qi++) cv[qi] += at[qi][k] * c;
    }
    const float wg0 = W_gen[tid], wg1 = W_gen[D_ + tid], wg2 = W_gen[2 * D_ + tid];
#pragma unroll
    for (int qi = 0; qi < 4; qi++) {
        const float dm = domainslots[((b * TQ_) + q0 + qi) * D_ + tid];
        float part = qv[qi][tid] * wg0 + cv[qi] * wg1 + dm * wg2;
#pragma unroll
        for (int off = 32; off; off >>= 1) part += __shfl_xor(part, off);
        if (lane == 0) red[w][qi] = part;
    }
    __syncthreads();
    if (tid < 4) {
        const float tot = red[0][tid] + red[1][tid] + red[2][tid] + red[3][tid] + b_gen[0];
        pg_out[b * TQ_ + q0 + tid] = 1.0f / (1.0f + __expf(-tot));
    }
    // store normalized attention
#pragma unroll
    for (int qi = 0; qi < 4; qi++) {
        attn_out[(b * TQ_ + q0 + qi) * TK_ + tid] = at[qi][tid];
        attn_out[(b * TQ_ + q0 + qi) * TK_ + 256 + tid] = at[qi][256 + tid];
    }
}

// ---------------- vocab GEMM: C = A(bf16) @ Wt^T(bf16), MODE 0: accumulate Z, MODE 1: write out
// BM=64, BN=128, BK=64, 4 waves (2x2), wave tile 32x64 -> 2x4 16x16 mfma tiles
template <int MODE>
__global__ __launch_bounds__(256) void gemm_vocab(
    const unsigned short* __restrict__ A,   // [1024][256] bf16
    const unsigned short* __restrict__ Bt,  // [32000][256] bf16 (transposed W)
    const float* __restrict__ b_state,
    const float* __restrict__ row_const,
    float* __restrict__ Z,
    float* __restrict__ out)
{
    __shared__ short Al[64][72];
    __shared__ short Bl[128][72];
    __shared__ float bst[128];
    __shared__ float rc[64];

    const int tid = threadIdx.x;
    const int bx = blockIdx.x;
    const int m0 = (bx & 15) * 64;
    const int n0 = (bx >> 4) * 128;

    if (tid < 128) bst[tid] = b_state[n0 + tid];
    if (MODE == 1 && tid < 64) rc[tid] = row_const[m0 + tid];

    const int wid = tid >> 6;
    const int lane = tid & 63;
    const int wm = wid & 1, wn = wid >> 1;
    const int quad = lane >> 4, l15 = lane & 15;

    f32x4 acc[2][4];
#pragma unroll
    for (int i = 0; i < 2; i++)
#pragma unroll
        for (int j = 0; j < 4; j++) acc[i][j] = f32x4{0.f, 0.f, 0.f, 0.f};

    for (int k0 = 0; k0 < D_; k0 += 64) {
        __syncthreads();
#pragma unroll
        for (int i = 0; i < 2; i++) {
            const int c = tid + i * 256;
            const int r = c >> 3, kc = (c & 7) * 8;
            *(uint4*)&Al[r][kc] = *(const uint4*)&A[(m0 + r) * D_ + k0 + kc];
        }
#pragma unroll
        for (int i = 0; i < 4; i++) {
            const int c = tid + i * 256;
            const int r = c >> 3, kc = (c & 7) * 8;
            *(uint4*)&Bl[r][kc] = *(const uint4*)&Bt[(n0 + r) * D_ + k0 + kc];
        }
        __syncthreads();
#pragma unroll
        for (int ks = 0; ks < 64; ks += 32) {
            short8 af[2], bf[4];
#pragma unroll
            for (int mt = 0; mt < 2; mt++)
                af[mt] = *(const short8*)&Al[wm * 32 + mt * 16 + l15][ks + quad * 8];
#pragma unroll
            for (int nt = 0; nt < 4; nt++)
                bf[nt] = *(const short8*)&Bl[wn * 64 + nt * 16 + l15][ks + quad * 8];
#pragma unroll
            for (int mt = 0; mt < 2; mt++)
#pragma unroll
                for (int nt = 0; nt < 4; nt++)
                    acc[mt][nt] = __builtin_amdgcn_mfma_f32_16x16x32_bf16(
                        af[mt], bf[nt], acc[mt][nt], 0, 0, 0);
        }
    }

    if (MODE == 0) {
        // Z accumulation: exp(logit) row sums (logits are small; no max needed)
        float rsum[2][4];
#pragma unroll
        for (int mt = 0; mt < 2; mt++)
#pragma unroll
            for (int r = 0; r < 4; r++) rsum[mt][r] = 0.f;
#pragma unroll
        for (int mt = 0; mt < 2; mt++)
#pragma unroll
            for (int nt = 0; nt < 4; nt++) {
                const float bcol = bst[wn * 64 + nt * 16 + l15];
#pragma unroll
                for (int r = 0; r < 4; r++)
                    rsum[mt][r] += __expf(acc[mt][nt][r] + bcol);
            }
#pragma unroll
        for (int mt = 0; mt < 2; mt++)
#pragma unroll
            for (int r = 0; r < 4; r++) {
                float v = rsum[mt][r];
                v += __shfl_xor(v, 1);
                v += __shfl_xor(v, 2);
                v += __shfl_xor(v, 4);
                v += __shfl_xor(v, 8);
                if (l15 == 0)
                    atomicAdd(&Z[m0 + wm * 32 + mt * 16 + quad * 4 + r], v);
            }
    } else {
        // final write: log(pg) - log(Z) + logit
#pragma unroll
        for (int mt = 0; mt < 2; mt++)
#pragma unroll
            for (int nt = 0; nt < 4; nt++) {
#pragma unroll
                for (int r = 0; r < 4; r++) {
                    const int rl = wm * 32 + mt * 16 + quad * 4 + r;
                    const int col = n0 + wn * 64 + nt * 16 + l15;
                    out[(m0 + rl) * V_ + col] =
                        rc[rl] + acc[mt][nt][r] + bst[wn * 64 + nt * 16 + l15];
                }
            }
    }
}

// ---------------- row_const = log(pg) - log(Z) ----------------
__global__ __launch_bounds__(256) void rowconst_kernel(
    const float* __restrict__ pg, const float* __restrict__ Z, float* __restrict__ rc)
{
    const int r = blockIdx.x * 256 + threadIdx.x;
    rc[r] = logf(pg[r]) - logf(Z[r]);
}

// ---------------- sparse pointer fixup: out = log(exp(out) + (1-pg)*attn_sum) ----------------
__global__ __launch_bounds__(256) void fixup_kernel(
    const int* __restrict__ cp, const int* __restrict__ nexta,
    const int* __restrict__ leader, const float* __restrict__ attn,
    const float* __restrict__ pg, float* __restrict__ out)
{
    const int t = blockIdx.x * 256 + threadIdx.x;   // [0, 1024*512)
    const int row = t >> 9, k = t & 511;
    const int b = row >> 6;
    if (!leader[b * TK_ + k]) return;
    float a = attn[row * TK_ + k];
    int j = nexta[b * TK_ + k];
    while (j >= 0) { a += attn[row * TK_ + j]; j = nexta[b * TK_ + j]; }
    const float val = (1.0f - pg[row]) * a;
    const int v = cp[b * TK_ + k];
    const int idx = row * V_ + v;
    out[idx] = logf(expf(out[idx]) + val);
}

extern "C" void kernel_launch(void* const* d_in, const int* in_sizes, int n_in,
                              void* d_out, int out_size, void* d_ws, size_t ws_size,
                              hipStream_t stream)
{
    const float* domainslots = (const float*)d_in[0];
    const float* out_states  = (const float*)d_in[1];
    const float* context     = (const float*)d_in[2];
    const int*   cp          = (const int*)d_in[3];
    const float* W_state     = (const float*)d_in[4];
    const float* b_state     = (const float*)d_in[5];
    const float* W_gen       = (const float*)d_in[6];
    const float* b_gen       = (const float*)d_in[7];
    float* out = (float*)d_out;
    char* ws = (char*)d_ws;

    // workspace layout (bytes)
    float* Z      = (float*)(ws);                    //  4 KB (1024 f32)
    float* pg     = (float*)(ws + 4096);             //  4 KB
    float* rc     = (float*)(ws + 8192);             //  4 KB
    float* attn   = (float*)(ws + 12288);            //  2 MB (1024*512 f32)
    int* nexta    = (int*)(ws + 2109440);            // 32 KB
    int* leader   = (int*)(ws + 2142208);            // 32 KB
    unsigned short* Ab = (unsigned short*)(ws + 2174976);  // 512 KB
    unsigned short* Wt = (unsigned short*)(ws + 2699264);  // 16 MB
    // total ~18.2 MB

    hipMemsetAsync(Z, 0, M_ * sizeof(float), stream);
    dedup_kernel<<<B_, 256, 0, stream>>>(cp, nexta, leader);
    conv_a_kernel<<<(M_ * D_) / 1024, 256, 0, stream>>>(out_states, Ab);
    conv_w_kernel<<<(D_ / 64) * (V_ / 64), 256, 0, stream>>>(W_state, Wt);
    stage_a_kernel<<<B_ * (TQ_ / 4), 256, 0, stream>>>(
        out_states, context, domainslots, W_gen, b_gen, attn, pg);
    gemm_vocab<0><<<(M_ / 64) * (V_ / 128), 256, 0, stream>>>(
        Ab, Wt, b_state, rc, Z, out);
    rowconst_kernel<<<M_ / 256, 256, 0, stream>>>(pg, Z, rc);
    gemm_vocab<1><<<(M_ / 64) * (V_ / 128), 256, 0, stream>>>(
        Ab, Wt, b_state, rc, Z, out);
    fixup_kernel<<<(M_ * TK_) / 256, 256, 0, stream>>>(
        cp, nexta, leader, attn, pg, out);
}

// Round 2
// 365.773 us; speedup vs baseline: 1.5734x; 1.5734x over previous
//
#include <hip/hip_runtime.h>
#include <math.h>

typedef short short8 __attribute__((ext_vector_type(8)));
typedef float f32x4 __attribute__((ext_vector_type(4)));

#define B_ 16
#define TQ_ 64
#define TK_ 512
#define D_ 256
#define V_ 32000
#define M_ (B_ * TQ_)   // 1024 rows

__device__ __forceinline__ unsigned short f2bf(float x) {
    unsigned int u = __float_as_uint(x);
    unsigned int r = (u + 0x7fffu + ((u >> 16) & 1u)) >> 16;
    return (unsigned short)r;
}

// ---------------- dedup: per-batch leader/next chains, branch-free scans ----------------
__global__ __launch_bounds__(256) void dedup_kernel(
    const int* __restrict__ cp, int* __restrict__ nexta, int* __restrict__ leader)
{
    __shared__ __align__(16) int c[TK_];
    const int b = blockIdx.x, tid = threadIdx.x;
    c[tid] = cp[b * TK_ + tid];
    c[tid + 256] = cp[b * TK_ + 256 + tid];
    __syncthreads();
    for (int k = tid; k < TK_; k += 256) {
        const int v = c[k];
        int fm = 1024, nx = 1024;
#pragma unroll 8
        for (int j0 = 0; j0 < TK_; j0 += 4) {
            const int4 q = *(const int4*)&c[j0];
            if (q.x == v) { fm = min(fm, j0);     if (j0     > k) nx = min(nx, j0);     }
            if (q.y == v) { fm = min(fm, j0 + 1); if (j0 + 1 > k) nx = min(nx, j0 + 1); }
            if (q.z == v) { fm = min(fm, j0 + 2); if (j0 + 2 > k) nx = min(nx, j0 + 2); }
            if (q.w == v) { fm = min(fm, j0 + 3); if (j0 + 3 > k) nx = min(nx, j0 + 3); }
        }
        nexta[b * TK_ + k] = (nx < 1024) ? nx : -1;
        leader[b * TK_ + k] = (fm == k) ? 1 : 0;
    }
}

// ---------------- convert out_states f32 -> bf16 (row-major [1024][256]) ----------------
__global__ __launch_bounds__(256) void conv_a_kernel(
    const float* __restrict__ A, unsigned short* __restrict__ Ab)
{
    const int i = (blockIdx.x * 256 + threadIdx.x) * 4;
    const float4 v = *(const float4*)&A[i];
    ushort4 o;
    o.x = f2bf(v.x); o.y = f2bf(v.y); o.z = f2bf(v.z); o.w = f2bf(v.w);
    *(ushort4*)&Ab[i] = o;
}

// ---------------- convert + transpose W_state [256][32000] f32 -> Wt [32000][256] bf16 ----
__global__ __launch_bounds__(256) void conv_w_kernel(
    const float* __restrict__ W, unsigned short* __restrict__ Wt)
{
    __shared__ float tile[64][65];
    const int tid = threadIdx.x;
    const int k0 = (blockIdx.x & 3) * 64;
    const int n0 = (blockIdx.x >> 2) * 64;
#pragma unroll
    for (int i = 0; i < 16; i++) {
        const int r = i * 4 + (tid >> 6), cc = tid & 63;
        tile[r][cc] = W[(k0 + r) * V_ + n0 + cc];
    }
    __syncthreads();
#pragma unroll
    for (int i = 0; i < 4; i++) {
        const int nl = i * 16 + (tid >> 4);
        const int kq = (tid & 15) * 4;
        ushort4 o;
        o.x = f2bf(tile[kq + 0][nl]);
        o.y = f2bf(tile[kq + 1][nl]);
        o.z = f2bf(tile[kq + 2][nl]);
        o.w = f2bf(tile[kq + 3][nl]);
        *(ushort4*)&Wt[(n0 + nl) * D_ + k0 + kq] = o;
    }
}

// ---------------- convert context: Cb bf16 [b][512][256] + Ct bf16 [b][256][512] ----------
__global__ __launch_bounds__(256) void conv_c_kernel(
    const float* __restrict__ ctx, unsigned short* __restrict__ Cb,
    unsigned short* __restrict__ Ct)
{
    __shared__ float tile[64][65];
    const int tid = threadIdx.x;
    const int b = blockIdx.x >> 5;
    const int r5 = blockIdx.x & 31;
    const int k0 = (r5 >> 2) * 64;
    const int d0 = (r5 & 3) * 64;
#pragma unroll
    for (int i = 0; i < 16; i++) {
        const int r = i * 4 + (tid >> 6), cc = tid & 63;
        const float v = ctx[((b * TK_) + k0 + r) * D_ + d0 + cc];
        tile[r][cc] = v;
        Cb[((b * TK_) + k0 + r) * D_ + d0 + cc] = f2bf(v);
    }
    __syncthreads();
#pragma unroll
    for (int i = 0; i < 4; i++) {
        const int dl = i * 16 + (tid >> 4);
        const int kq = (tid & 15) * 4;
        ushort4 o;
        o.x = f2bf(tile[kq + 0][dl]);
        o.y = f2bf(tile[kq + 1][dl]);
        o.z = f2bf(tile[kq + 2][dl]);
        o.w = f2bf(tile[kq + 3][dl]);
        *(ushort4*)&Ct[((b * D_) + d0 + dl) * TK_ + k0 + kq] = o;
    }
}

// ---------------- small batched GEMM: C[b] = A[b] @ Bt[b]^T (both bf16, K-contiguous) ----
// BM=64, BN=128, BK=64, 4 waves (2x2), wave tile 32x64 -> 2x4 16x16 mfma tiles.
template <int LDA, int LDB, int KTOT>
__global__ __launch_bounds__(256) void gemm_small(
    const unsigned short* __restrict__ A,
    const unsigned short* __restrict__ Bt,
    float* __restrict__ C, int ldc, int nchunks, int btrows, float scale)
{
    __shared__ short Al[64][72];
    __shared__ short Bl[128][72];
    const int tid = threadIdx.x;
    const int b = blockIdx.x / nchunks;
    const int n0 = (blockIdx.x % nchunks) * 128;
    A += (size_t)b * 64 * LDA;
    Bt += (size_t)b * btrows * LDB;
    C += (size_t)b * 64 * ldc;

    const int wid = tid >> 6;
    const int lane = tid & 63;
    const int wm = wid & 1, wn = wid >> 1;
    const int quad = lane >> 4, l15 = lane & 15;

    f32x4 acc[2][4];
#pragma unroll
    for (int i = 0; i < 2; i++)
#pragma unroll
        for (int j = 0; j < 4; j++) acc[i][j] = f32x4{0.f, 0.f, 0.f, 0.f};

    for (int k0 = 0; k0 < KTOT; k0 += 64) {
        __syncthreads();
#pragma unroll
        for (int i = 0; i < 2; i++) {
            const int c = tid + i * 256;
            const int r = c >> 3, kc = (c & 7) * 8;
            *(uint4*)&Al[r][kc] = *(const uint4*)&A[r * LDA + k0 + kc];
        }
#pragma unroll
        for (int i = 0; i < 4; i++) {
            const int c = tid + i * 256;
            const int r = c >> 3, kc = (c & 7) * 8;
            *(uint4*)&Bl[r][kc] = *(const uint4*)&Bt[(n0 + r) * LDB + k0 + kc];
        }
        __syncthreads();
#pragma unroll
        for (int ks = 0; ks < 64; ks += 32) {
            short8 af[2], bf[4];
#pragma unroll
            for (int mt = 0; mt < 2; mt++)
                af[mt] = *(const short8*)&Al[wm * 32 + mt * 16 + l15][ks + quad * 8];
#pragma unroll
            for (int nt = 0; nt < 4; nt++)
                bf[nt] = *(const short8*)&Bl[wn * 64 + nt * 16 + l15][ks + quad * 8];
#pragma unroll
            for (int mt = 0; mt < 2; mt++)
#pragma unroll
                for (int nt = 0; nt < 4; nt++)
                    acc[mt][nt] = __builtin_amdgcn_mfma_f32_16x16x32_bf16(
                        af[mt], bf[nt], acc[mt][nt], 0, 0, 0);
        }
    }
#pragma unroll
    for (int mt = 0; mt < 2; mt++)
#pragma unroll
        for (int nt = 0; nt < 4; nt++)
#pragma unroll
            for (int r = 0; r < 4; r++) {
                const int rl = wm * 32 + mt * 16 + quad * 4 + r;
                const int col = n0 + wn * 64 + nt * 16 + l15;
                C[rl * ldc + col] = acc[mt][nt][r] * scale;
            }
}

// ---------------- softmax over S rows; write attn f32 in-place + P bf16 ----------------
__global__ __launch_bounds__(256) void softmax_kernel(
    float* __restrict__ S, unsigned short* __restrict__ Pb)
{
    const int w = threadIdx.x >> 6, lane = threadIdx.x & 63;
    const int row = blockIdx.x * 4 + w;
    float v[8], m = -1e30f;
#pragma unroll
    for (int j = 0; j < 8; j++) { v[j] = S[row * TK_ + lane + 64 * j]; m = fmaxf(m, v[j]); }
#pragma unroll
    for (int off = 32; off; off >>= 1) m = fmaxf(m, __shfl_xor(m, off));
    float s = 0.f;
#pragma unroll
    for (int j = 0; j < 8; j++) { v[j] = __expf(v[j] - m); s += v[j]; }
#pragma unroll
    for (int off = 32; off; off >>= 1) s += __shfl_xor(s, off);
    const float inv = 1.0f / s;
#pragma unroll
    for (int j = 0; j < 8; j++) {
        const float p = v[j] * inv;
        S[row * TK_ + lane + 64 * j] = p;
        Pb[row * TK_ + lane + 64 * j] = f2bf(p);
    }
}

// ---------------- p_gen: sigmoid(os.wg0 + cv.wg1 + dm.wg2 + b) per row ----------------
__global__ __launch_bounds__(256) void pgen_kernel(
    const float* __restrict__ os, const float* __restrict__ cv,
    const float* __restrict__ dm, const float* __restrict__ W_gen,
    const float* __restrict__ b_gen, float* __restrict__ pg)
{
    const int w = threadIdx.x >> 6, lane = threadIdx.x & 63;
    const int row = blockIdx.x * 4 + w;
    const int d4 = lane * 4;
    const float4 o4 = *(const float4*)&os[row * D_ + d4];
    const float4 c4 = *(const float4*)&cv[row * D_ + d4];
    const float4 m4 = *(const float4*)&dm[row * D_ + d4];
    const float4 w0 = *(const float4*)&W_gen[d4];
    const float4 w1 = *(const float4*)&W_gen[D_ + d4];
    const float4 w2 = *(const float4*)&W_gen[2 * D_ + d4];
    float p = o4.x * w0.x + o4.y * w0.y + o4.z * w0.z + o4.w * w0.w
            + c4.x * w1.x + c4.y * w1.y + c4.z * w1.z + c4.w * w1.w
            + m4.x * w2.x + m4.y * w2.y + m4.z * w2.z + m4.w * w2.w;
#pragma unroll
    for (int off = 32; off; off >>= 1) p += __shfl_xor(p, off);
    if (lane == 0) pg[row] = 1.0f / (1.0f + __expf(-(p + b_gen[0])));
}

// ---------------- vocab GEMM: MODE 0: accumulate Z, MODE 1: write out ----------------
template <int MODE>
__global__ __launch_bounds__(256) void gemm_vocab(
    const unsigned short* __restrict__ A,   // [1024][256] bf16
    const unsigned short* __restrict__ Bt,  // [32000][256] bf16
    const float* __restrict__ b_state,
    const float* __restrict__ row_const,
    float* __restrict__ Z,
    float* __restrict__ out)
{
    __shared__ short Al[64][72];
    __shared__ short Bl[128][72];
    __shared__ float bst[128];
    __shared__ float rc[64];

    const int tid = threadIdx.x;
    const int bx = blockIdx.x;
    const int m0 = (bx & 15) * 64;
    const int n0 = (bx >> 4) * 128;

    if (tid < 128) bst[tid] = b_state[n0 + tid];
    if (MODE == 1 && tid < 64) rc[tid] = row_const[m0 + tid];

    const int wid = tid >> 6;
    const int lane = tid & 63;
    const int wm = wid & 1, wn = wid >> 1;
    const int quad = lane >> 4, l15 = lane & 15;

    f32x4 acc[2][4];
#pragma unroll
    for (int i = 0; i < 2; i++)
#pragma unroll
        for (int j = 0; j < 4; j++) acc[i][j] = f32x4{0.f, 0.f, 0.f, 0.f};

    for (int k0 = 0; k0 < D_; k0 += 64) {
        __syncthreads();
#pragma unroll
        for (int i = 0; i < 2; i++) {
            const int c = tid + i * 256;
            const int r = c >> 3, kc = (c & 7) * 8;
            *(uint4*)&Al[r][kc] = *(const uint4*)&A[(m0 + r) * D_ + k0 + kc];
        }
#pragma unroll
        for (int i = 0; i < 4; i++) {
            const int c = tid + i * 256;
            const int r = c >> 3, kc = (c & 7) * 8;
            *(uint4*)&Bl[r][kc] = *(const uint4*)&Bt[(n0 + r) * D_ + k0 + kc];
        }
        __syncthreads();
#pragma unroll
        for (int ks = 0; ks < 64; ks += 32) {
            short8 af[2], bf[4];
#pragma unroll
            for (int mt = 0; mt < 2; mt++)
                af[mt] = *(const short8*)&Al[wm * 32 + mt * 16 + l15][ks + quad * 8];
#pragma unroll
            for (int nt = 0; nt < 4; nt++)
                bf[nt] = *(const short8*)&Bl[wn * 64 + nt * 16 + l15][ks + quad * 8];
#pragma unroll
            for (int mt = 0; mt < 2; mt++)
#pragma unroll
                for (int nt = 0; nt < 4; nt++)
                    acc[mt][nt] = __builtin_amdgcn_mfma_f32_16x16x32_bf16(
                        af[mt], bf[nt], acc[mt][nt], 0, 0, 0);
        }
    }

    if (MODE == 0) {
        float rsum[2][4];
#pragma unroll
        for (int mt = 0; mt < 2; mt++)
#pragma unroll
            for (int r = 0; r < 4; r++) rsum[mt][r] = 0.f;
#pragma unroll
        for (int mt = 0; mt < 2; mt++)
#pragma unroll
            for (int nt = 0; nt < 4; nt++) {
                const float bcol = bst[wn * 64 + nt * 16 + l15];
#pragma unroll
                for (int r = 0; r < 4; r++)
                    rsum[mt][r] += __expf(acc[mt][nt][r] + bcol);
            }
#pragma unroll
        for (int mt = 0; mt < 2; mt++)
#pragma unroll
            for (int r = 0; r < 4; r++) {
                float v = rsum[mt][r];
                v += __shfl_xor(v, 1);
                v += __shfl_xor(v, 2);
                v += __shfl_xor(v, 4);
                v += __shfl_xor(v, 8);
                if (l15 == 0)
                    atomicAdd(&Z[m0 + wm * 32 + mt * 16 + quad * 4 + r], v);
            }
    } else {
#pragma unroll
        for (int mt = 0; mt < 2; mt++)
#pragma unroll
            for (int nt = 0; nt < 4; nt++) {
#pragma unroll
                for (int r = 0; r < 4; r++) {
                    const int rl = wm * 32 + mt * 16 + quad * 4 + r;
                    const int col = n0 + wn * 64 + nt * 16 + l15;
                    out[(size_t)(m0 + rl) * V_ + col] =
                        rc[rl] + acc[mt][nt][r] + bst[wn * 64 + nt * 16 + l15];
                }
            }
    }
}

// ---------------- row_const = log(pg) - log(Z) ----------------
__global__ __launch_bounds__(256) void rowconst_kernel(
    const float* __restrict__ pg, const float* __restrict__ Z, float* __restrict__ rc)
{
    const int r = blockIdx.x * 256 + threadIdx.x;
    rc[r] = logf(pg[r]) - logf(Z[r]);
}

// ---------------- sparse pointer fixup ----------------
__global__ __launch_bounds__(256) void fixup_kernel(
    const int* __restrict__ cp, const int* __restrict__ nexta,
    const int* __restrict__ leader, const float* __restrict__ attn,
    const float* __restrict__ pg, float* __restrict__ out)
{
    const int t = blockIdx.x * 256 + threadIdx.x;
    const int row = t >> 9, k = t & 511;
    const int b = row >> 6;
    if (!leader[b * TK_ + k]) return;
    float a = attn[row * TK_ + k];
    int j = nexta[b * TK_ + k];
    while (j >= 0) { a += attn[row * TK_ + j]; j = nexta[b * TK_ + j]; }
    const float val = (1.0f - pg[row]) * a;
    const int v = cp[b * TK_ + k];
    const size_t idx = (size_t)row * V_ + v;
    out[idx] = logf(expf(out[idx]) + val);
}

extern "C" void kernel_launch(void* const* d_in, const int* in_sizes, int n_in,
                              void* d_out, int out_size, void* d_ws, size_t ws_size,
                              hipStream_t stream)
{
    const float* domainslots = (const float*)d_in[0];
    const float* out_states  = (const float*)d_in[1];
    const float* context     = (const float*)d_in[2];
    const int*   cp          = (const int*)d_in[3];
    const float* W_state     = (const float*)d_in[4];
    const float* b_state     = (const float*)d_in[5];
    const float* W_gen       = (const float*)d_in[6];
    const float* b_gen       = (const float*)d_in[7];
    float* out = (float*)d_out;
    char* ws = (char*)d_ws;

    // workspace layout (bytes)
    float* Z      = (float*)(ws);                          //  4 KB
    float* pg     = (float*)(ws + 4096);                   //  4 KB
    float* rc     = (float*)(ws + 8192);                   //  4 KB
    float* S      = (float*)(ws + 12288);                  //  2 MB (scores -> attn in place)
    int* nexta    = (int*)(ws + 2109440);                  // 32 KB
    int* leader   = (int*)(ws + 2142208);                  // 32 KB
    unsigned short* Ab = (unsigned short*)(ws + 2174976);  // 512 KB
    unsigned short* Wt = (unsigned short*)(ws + 2699264);  // 16 MB -> ends 19083264
    unsigned short* Cb = (unsigned short*)(ws + 19083264); // 4 MB
    unsigned short* Ct = (unsigned short*)(ws + 23277568); // 4 MB
    unsigned short* Pb = (unsigned short*)(ws + 27471872); // 1 MB
    float* cv     = (float*)(ws + 28520448);               // 1 MB -> ends ~29.6 MB

    hipMemsetAsync(Z, 0, M_ * sizeof(float), stream);
    dedup_kernel<<<B_, 256, 0, stream>>>(cp, nexta, leader);
    conv_a_kernel<<<(M_ * D_) / 1024, 256, 0, stream>>>(out_states, Ab);
    conv_w_kernel<<<(D_ / 64) * (V_ / 64), 256, 0, stream>>>(W_state, Wt);
    conv_c_kernel<<<B_ * 32, 256, 0, stream>>>(context, Cb, Ct);

    // S = Ab @ Cb^T / 16 : per batch M=64,N=512,K=256
    gemm_small<D_, D_, D_><<<B_ * 4, 256, 0, stream>>>(Ab, Cb, S, TK_, 4, TK_, 0.0625f);
    softmax_kernel<<<M_ / 4, 256, 0, stream>>>(S, Pb);
    // cv = P @ C : per batch M=64,N=256,K=512 (Bt = Ct)
    gemm_small<TK_, TK_, TK_><<<B_ * 2, 256, 0, stream>>>(Pb, Ct, cv, D_, 2, D_, 1.0f);
    pgen_kernel<<<M_ / 4, 256, 0, stream>>>(out_states, cv, domainslots, W_gen, b_gen, pg);

    gemm_vocab<0><<<(M_ / 64) * (V_ / 128), 256, 0, stream>>>(Ab, Wt, b_state, rc, Z, out);
    rowconst_kernel<<<M_ / 256, 256, 0, stream>>>(pg, Z, rc);
    gemm_vocab<1><<<(M_ / 64) * (V_ / 128), 256, 0, stream>>>(Ab, Wt, b_state, rc, Z, out);
    fixup_kernel<<<(M_ * TK_) / 256, 256, 0, stream>>>(cp, nexta, leader, S, pg, out);
}

// Round 3
// 349.089 us; speedup vs baseline: 1.6486x; 1.0478x over previous
//
#include <hip/hip_runtime.h>
#include <math.h>

typedef short short8 __attribute__((ext_vector_type(8)));
typedef float f32x4 __attribute__((ext_vector_type(4)));

#define B_ 16
#define TQ_ 64
#define TK_ 512
#define D_ 256
#define V_ 32000
#define M_ (B_ * TQ_)   // 1024 rows

__device__ __forceinline__ unsigned short f2bf(float x) {
    unsigned int u = __float_as_uint(x);
    unsigned int r = (u + 0x7fffu + ((u >> 16) & 1u)) >> 16;
    return (unsigned short)r;
}

__device__ __forceinline__ void gload_lds16(const void* g, void* l) {
    __builtin_amdgcn_global_load_lds(
        (const __attribute__((address_space(1))) void*)g,
        (__attribute__((address_space(3))) void*)l, 16, 0, 0);
}

// ---------------- dedup: per-batch leader/next chains, branch-free scans ----------------
__global__ __launch_bounds__(256) void dedup_kernel(
    const int* __restrict__ cp, int* __restrict__ nexta, int* __restrict__ leader)
{
    __shared__ __align__(16) int c[TK_];
    const int b = blockIdx.x, tid = threadIdx.x;
    c[tid] = cp[b * TK_ + tid];
    c[tid + 256] = cp[b * TK_ + 256 + tid];
    __syncthreads();
    for (int k = tid; k < TK_; k += 256) {
        const int v = c[k];
        int fm = 1024, nx = 1024;
#pragma unroll 8
        for (int j0 = 0; j0 < TK_; j0 += 4) {
            const int4 q = *(const int4*)&c[j0];
            if (q.x == v) { fm = min(fm, j0);     if (j0     > k) nx = min(nx, j0);     }
            if (q.y == v) { fm = min(fm, j0 + 1); if (j0 + 1 > k) nx = min(nx, j0 + 1); }
            if (q.z == v) { fm = min(fm, j0 + 2); if (j0 + 2 > k) nx = min(nx, j0 + 2); }
            if (q.w == v) { fm = min(fm, j0 + 3); if (j0 + 3 > k) nx = min(nx, j0 + 3); }
        }
        nexta[b * TK_ + k] = (nx < 1024) ? nx : -1;
        leader[b * TK_ + k] = (fm == k) ? 1 : 0;
    }
}

// ---------------- convert out_states f32 -> bf16 (row-major [1024][256]) ----------------
__global__ __launch_bounds__(256) void conv_a_kernel(
    const float* __restrict__ A, unsigned short* __restrict__ Ab)
{
    const int i = (blockIdx.x * 256 + threadIdx.x) * 4;
    const float4 v = *(const float4*)&A[i];
    ushort4 o;
    o.x = f2bf(v.x); o.y = f2bf(v.y); o.z = f2bf(v.z); o.w = f2bf(v.w);
    *(ushort4*)&Ab[i] = o;
}

// ---------------- convert + transpose W_state [256][32000] f32 -> Wt [32000][256] bf16 ----
__global__ __launch_bounds__(256) void conv_w_kernel(
    const float* __restrict__ W, unsigned short* __restrict__ Wt)
{
    __shared__ float tile[64][65];
    const int tid = threadIdx.x;
    const int k0 = (blockIdx.x & 3) * 64;
    const int n0 = (blockIdx.x >> 2) * 64;
#pragma unroll
    for (int i = 0; i < 16; i++) {
        const int r = i * 4 + (tid >> 6), cc = tid & 63;
        tile[r][cc] = W[(k0 + r) * V_ + n0 + cc];
    }
    __syncthreads();
#pragma unroll
    for (int i = 0; i < 4; i++) {
        const int nl = i * 16 + (tid >> 4);
        const int kq = (tid & 15) * 4;
        ushort4 o;
        o.x = f2bf(tile[kq + 0][nl]);
        o.y = f2bf(tile[kq + 1][nl]);
        o.z = f2bf(tile[kq + 2][nl]);
        o.w = f2bf(tile[kq + 3][nl]);
        *(ushort4*)&Wt[(n0 + nl) * D_ + k0 + kq] = o;
    }
}

// ---------------- convert context: Cb bf16 [b][512][256] + Ct bf16 [b][256][512] ----------
__global__ __launch_bounds__(256) void conv_c_kernel(
    const float* __restrict__ ctx, unsigned short* __restrict__ Cb,
    unsigned short* __restrict__ Ct)
{
    __shared__ float tile[64][65];
    const int tid = threadIdx.x;
    const int b = blockIdx.x >> 5;
    const int r5 = blockIdx.x & 31;
    const int k0 = (r5 >> 2) * 64;
    const int d0 = (r5 & 3) * 64;
#pragma unroll
    for (int i = 0; i < 16; i++) {
        const int r = i * 4 + (tid >> 6), cc = tid & 63;
        const float v = ctx[((b * TK_) + k0 + r) * D_ + d0 + cc];
        tile[r][cc] = v;
        Cb[((b * TK_) + k0 + r) * D_ + d0 + cc] = f2bf(v);
    }
    __syncthreads();
#pragma unroll
    for (int i = 0; i < 4; i++) {
        const int dl = i * 16 + (tid >> 4);
        const int kq = (tid & 15) * 4;
        ushort4 o;
        o.x = f2bf(tile[kq + 0][dl]);
        o.y = f2bf(tile[kq + 1][dl]);
        o.z = f2bf(tile[kq + 2][dl]);
        o.w = f2bf(tile[kq + 3][dl]);
        *(ushort4*)&Ct[((b * D_) + d0 + dl) * TK_ + k0 + kq] = o;
    }
}

// ---------------- small batched GEMM: C[b] = A[b] @ Bt[b]^T (both bf16, K-contiguous) ----
template <int LDA, int LDB, int KTOT>
__global__ __launch_bounds__(256) void gemm_small(
    const unsigned short* __restrict__ A,
    const unsigned short* __restrict__ Bt,
    float* __restrict__ C, int ldc, int nchunks, int btrows, float scale)
{
    __shared__ short Al[64][72];
    __shared__ short Bl[128][72];
    const int tid = threadIdx.x;
    const int b = blockIdx.x / nchunks;
    const int n0 = (blockIdx.x % nchunks) * 128;
    A += (size_t)b * 64 * LDA;
    Bt += (size_t)b * btrows * LDB;
    C += (size_t)b * 64 * ldc;

    const int wid = tid >> 6;
    const int lane = tid & 63;
    const int wm = wid & 1, wn = wid >> 1;
    const int quad = lane >> 4, l15 = lane & 15;

    f32x4 acc[2][4];
#pragma unroll
    for (int i = 0; i < 2; i++)
#pragma unroll
        for (int j = 0; j < 4; j++) acc[i][j] = f32x4{0.f, 0.f, 0.f, 0.f};

    for (int k0 = 0; k0 < KTOT; k0 += 64) {
        __syncthreads();
#pragma unroll
        for (int i = 0; i < 2; i++) {
            const int c = tid + i * 256;
            const int r = c >> 3, kc = (c & 7) * 8;
            *(uint4*)&Al[r][kc] = *(const uint4*)&A[r * LDA + k0 + kc];
        }
#pragma unroll
        for (int i = 0; i < 4; i++) {
            const int c = tid + i * 256;
            const int r = c >> 3, kc = (c & 7) * 8;
            *(uint4*)&Bl[r][kc] = *(const uint4*)&Bt[(n0 + r) * LDB + k0 + kc];
        }
        __syncthreads();
#pragma unroll
        for (int ks = 0; ks < 64; ks += 32) {
            short8 af[2], bf[4];
#pragma unroll
            for (int mt = 0; mt < 2; mt++)
                af[mt] = *(const short8*)&Al[wm * 32 + mt * 16 + l15][ks + quad * 8];
#pragma unroll
            for (int nt = 0; nt < 4; nt++)
                bf[nt] = *(const short8*)&Bl[wn * 64 + nt * 16 + l15][ks + quad * 8];
#pragma unroll
            for (int mt = 0; mt < 2; mt++)
#pragma unroll
                for (int nt = 0; nt < 4; nt++)
                    acc[mt][nt] = __builtin_amdgcn_mfma_f32_16x16x32_bf16(
                        af[mt], bf[nt], acc[mt][nt], 0, 0, 0);
        }
    }
#pragma unroll
    for (int mt = 0; mt < 2; mt++)
#pragma unroll
        for (int nt = 0; nt < 4; nt++)
#pragma unroll
            for (int r = 0; r < 4; r++) {
                const int rl = wm * 32 + mt * 16 + quad * 4 + r;
                const int col = n0 + wn * 64 + nt * 16 + l15;
                C[rl * ldc + col] = acc[mt][nt][r] * scale;
            }
}

// ---------------- softmax over S rows; write attn f32 in-place + P bf16 ----------------
__global__ __launch_bounds__(256) void softmax_kernel(
    float* __restrict__ S, unsigned short* __restrict__ Pb)
{
    const int w = threadIdx.x >> 6, lane = threadIdx.x & 63;
    const int row = blockIdx.x * 4 + w;
    float v[8], m = -1e30f;
#pragma unroll
    for (int j = 0; j < 8; j++) { v[j] = S[row * TK_ + lane + 64 * j]; m = fmaxf(m, v[j]); }
#pragma unroll
    for (int off = 32; off; off >>= 1) m = fmaxf(m, __shfl_xor(m, off));
    float s = 0.f;
#pragma unroll
    for (int j = 0; j < 8; j++) { v[j] = __expf(v[j] - m); s += v[j]; }
#pragma unroll
    for (int off = 32; off; off >>= 1) s += __shfl_xor(s, off);
    const float inv = 1.0f / s;
#pragma unroll
    for (int j = 0; j < 8; j++) {
        const float p = v[j] * inv;
        S[row * TK_ + lane + 64 * j] = p;
        Pb[row * TK_ + lane + 64 * j] = f2bf(p);
    }
}

// ---------------- p_gen: sigmoid(os.wg0 + cv.wg1 + dm.wg2 + b) per row ----------------
__global__ __launch_bounds__(256) void pgen_kernel(
    const float* __restrict__ os, const float* __restrict__ cv,
    const float* __restrict__ dm, const float* __restrict__ W_gen,
    const float* __restrict__ b_gen, float* __restrict__ pg)
{
    const int w = threadIdx.x >> 6, lane = threadIdx.x & 63;
    const int row = blockIdx.x * 4 + w;
    const int d4 = lane * 4;
    const float4 o4 = *(const float4*)&os[row * D_ + d4];
    const float4 c4 = *(const float4*)&cv[row * D_ + d4];
    const float4 m4 = *(const float4*)&dm[row * D_ + d4];
    const float4 w0 = *(const float4*)&W_gen[d4];
    const float4 w1 = *(const float4*)&W_gen[D_ + d4];
    const float4 w2 = *(const float4*)&W_gen[2 * D_ + d4];
    float p = o4.x * w0.x + o4.y * w0.y + o4.z * w0.z + o4.w * w0.w
            + c4.x * w1.x + c4.y * w1.y + c4.z * w1.z + c4.w * w1.w
            + m4.x * w2.x + m4.y * w2.y + m4.z * w2.z + m4.w * w2.w;
#pragma unroll
    for (int off = 32; off; off >>= 1) p += __shfl_xor(p, off);
    if (lane == 0) pg[row] = 1.0f / (1.0f + __expf(-(p + b_gen[0])));
}

// ---------------- fused vocab GEMM: f32 logits -> out, exp-rowsum -> Z (atomics) --------
// BM=BN=128, BK=64, 4 waves (2x2), wave tile 64x64 = 4x4 16x16x32 mfma.
// Staging via global_load_lds width=16 (no LDS pad; wave-uniform base + lane*16).
__global__ __launch_bounds__(256) void gemm_vocab_fused(
    const unsigned short* __restrict__ A,   // [1024][256] bf16
    const unsigned short* __restrict__ Bt,  // [32000][256] bf16
    const float* __restrict__ b_state,
    float* __restrict__ Z,
    float* __restrict__ out)
{
    __shared__ short Al[128][64];   // 16 KB
    __shared__ short Bl[128][64];   // 16 KB
    __shared__ float bst[128];

    const int tid = threadIdx.x;
    const int bx = blockIdx.x;
    const int m0 = (bx & 7) * 128;     // m-major: consecutive blocks share Wt tile
    const int n0 = (bx >> 3) * 128;

    if (tid < 128) bst[tid] = b_state[n0 + tid];

    const int wid = tid >> 6, lane = tid & 63;
    const int wm = wid & 1, wn = wid >> 1;
    const int quad = lane >> 4, l15 = lane & 15;
    const int srow = lane >> 3;          // 0..7 row within 8-row staging chunk
    const int scol = (lane & 7) * 8;     // short col 0..56

    f32x4 acc[4][4];
#pragma unroll
    for (int i = 0; i < 4; i++)
#pragma unroll
        for (int j = 0; j < 4; j++) acc[i][j] = f32x4{0.f, 0.f, 0.f, 0.f};

    for (int k0 = 0; k0 < D_; k0 += 64) {
        __syncthreads();
#pragma unroll
        for (int j = 0; j < 4; j++) {
            const int c = j * 4 + wid;           // chunk 0..15 (8 rows each)
            const int r = c * 8 + srow;
            gload_lds16(&A[(size_t)(m0 + r) * D_ + k0 + scol], &Al[c * 8][0]);
        }
#pragma unroll
        for (int j = 0; j < 4; j++) {
            const int c = j * 4 + wid;
            const int r = c * 8 + srow;
            gload_lds16(&Bt[(size_t)(n0 + r) * D_ + k0 + scol], &Bl[c * 8][0]);
        }
        __syncthreads();
#pragma unroll
        for (int ks = 0; ks < 64; ks += 32) {
            short8 af[4], bf[4];
#pragma unroll
            for (int mt = 0; mt < 4; mt++)
                af[mt] = *(const short8*)&Al[wm * 64 + mt * 16 + l15][ks + quad * 8];
#pragma unroll
            for (int nt = 0; nt < 4; nt++)
                bf[nt] = *(const short8*)&Bl[wn * 64 + nt * 16 + l15][ks + quad * 8];
#pragma unroll
            for (int mt = 0; mt < 4; mt++)
#pragma unroll
                for (int nt = 0; nt < 4; nt++)
                    acc[mt][nt] = __builtin_amdgcn_mfma_f32_16x16x32_bf16(
                        af[mt], bf[nt], acc[mt][nt], 0, 0, 0);
        }
    }

    // store f32 logits + accumulate Z = sum(exp(logit)) per row
#pragma unroll
    for (int mt = 0; mt < 4; mt++) {
        float rs[4] = {0.f, 0.f, 0.f, 0.f};
#pragma unroll
        for (int nt = 0; nt < 4; nt++) {
            const float bcol = bst[wn * 64 + nt * 16 + l15];
#pragma unroll
            for (int r = 0; r < 4; r++) {
                const int row = wm * 64 + mt * 16 + quad * 4 + r;
                const int col = wn * 64 + nt * 16 + l15;
                const float v = acc[mt][nt][r] + bcol;
                out[(size_t)(m0 + row) * V_ + n0 + col] = v;
                rs[r] += __expf(v);
            }
        }
#pragma unroll
        for (int r = 0; r < 4; r++) {
            float v = rs[r];
            v += __shfl_xor(v, 1);
            v += __shfl_xor(v, 2);
            v += __shfl_xor(v, 4);
            v += __shfl_xor(v, 8);
            if (l15 == 0)
                atomicAdd(&Z[m0 + wm * 64 + mt * 16 + quad * 4 + r], v);
        }
    }
}

// ---------------- row_const = log(pg) - log(Z) ----------------
__global__ __launch_bounds__(256) void rowconst_kernel(
    const float* __restrict__ pg, const float* __restrict__ Z, float* __restrict__ rc)
{
    const int r = blockIdx.x * 256 + threadIdx.x;
    rc[r] = logf(pg[r]) - logf(Z[r]);
}

// ---------------- epilogue: out[row][*] += rc[row], in place ----------------
__global__ __launch_bounds__(256) void epilogue_kernel(
    const float* __restrict__ rc, float* __restrict__ out)
{
    const int row = blockIdx.x;
    const float r = rc[row];
    float4* p = (float4*)(out + (size_t)row * V_);
    for (int i = threadIdx.x; i < V_ / 4; i += 256) {
        float4 v = p[i];
        v.x += r; v.y += r; v.z += r; v.w += r;
        p[i] = v;
    }
}

// ---------------- sparse pointer fixup ----------------
__global__ __launch_bounds__(256) void fixup_kernel(
    const int* __restrict__ cp, const int* __restrict__ nexta,
    const int* __restrict__ leader, const float* __restrict__ attn,
    const float* __restrict__ pg, float* __restrict__ out)
{
    const int t = blockIdx.x * 256 + threadIdx.x;
    const int row = t >> 9, k = t & 511;
    const int b = row >> 6;
    if (!leader[b * TK_ + k]) return;
    float a = attn[row * TK_ + k];
    int j = nexta[b * TK_ + k];
    while (j >= 0) { a += attn[row * TK_ + j]; j = nexta[b * TK_ + j]; }
    const float val = (1.0f - pg[row]) * a;
    const int v = cp[b * TK_ + k];
    const size_t idx = (size_t)row * V_ + v;
    out[idx] = logf(expf(out[idx]) + val);
}

extern "C" void kernel_launch(void* const* d_in, const int* in_sizes, int n_in,
                              void* d_out, int out_size, void* d_ws, size_t ws_size,
                              hipStream_t stream)
{
    const float* domainslots = (const float*)d_in[0];
    const float* out_states  = (const float*)d_in[1];
    const float* context     = (const float*)d_in[2];
    const int*   cp          = (const int*)d_in[3];
    const float* W_state     = (const float*)d_in[4];
    const float* b_state     = (const float*)d_in[5];
    const float* W_gen       = (const float*)d_in[6];
    const float* b_gen       = (const float*)d_in[7];
    float* out = (float*)d_out;
    char* ws = (char*)d_ws;

    // workspace layout (bytes)
    float* Z      = (float*)(ws);                          //  4 KB
    float* pg     = (float*)(ws + 4096);                   //  4 KB
    float* rc     = (float*)(ws + 8192);                   //  4 KB
    float* S      = (float*)(ws + 12288);                  //  2 MB (scores -> attn in place)
    int* nexta    = (int*)(ws + 2109440);                  // 32 KB
    int* leader   = (int*)(ws + 2142208);                  // 32 KB
    unsigned short* Ab = (unsigned short*)(ws + 2174976);  // 512 KB
    unsigned short* Wt = (unsigned short*)(ws + 2699264);  // 16 MB -> ends 19083264
    unsigned short* Cb = (unsigned short*)(ws + 19083264); // 4 MB
    unsigned short* Ct = (unsigned short*)(ws + 23277568); // 4 MB
    unsigned short* Pb = (unsigned short*)(ws + 27471872); // 1 MB
    float* cv     = (float*)(ws + 28520448);               // 1 MB -> ends ~29.6 MB

    hipMemsetAsync(Z, 0, M_ * sizeof(float), stream);
    dedup_kernel<<<B_, 256, 0, stream>>>(cp, nexta, leader);
    conv_a_kernel<<<(M_ * D_) / 1024, 256, 0, stream>>>(out_states, Ab);
    conv_w_kernel<<<(D_ / 64) * (V_ / 64), 256, 0, stream>>>(W_state, Wt);
    conv_c_kernel<<<B_ * 32, 256, 0, stream>>>(context, Cb, Ct);

    // S = Ab @ Cb^T / 16 : per batch M=64,N=512,K=256
    gemm_small<D_, D_, D_><<<B_ * 4, 256, 0, stream>>>(Ab, Cb, S, TK_, 4, TK_, 0.0625f);
    softmax_kernel<<<M_ / 4, 256, 0, stream>>>(S, Pb);
    // cv = P @ C : per batch M=64,N=256,K=512 (Bt = Ct)
    gemm_small<TK_, TK_, TK_><<<B_ * 2, 256, 0, stream>>>(Pb, Ct, cv, D_, 2, D_, 1.0f);
    pgen_kernel<<<M_ / 4, 256, 0, stream>>>(out_states, cv, domainslots, W_gen, b_gen, pg);

    // single-pass vocab GEMM: f32 logits into out + Z
    gemm_vocab_fused<<<(M_ / 128) * (V_ / 128), 256, 0, stream>>>(Ab, Wt, b_state, Z, out);
    rowconst_kernel<<<M_ / 256, 256, 0, stream>>>(pg, Z, rc);
    epilogue_kernel<<<M_, 256, 0, stream>>>(rc, out);
    fixup_kernel<<<(M_ * TK_) / 256, 256, 0, stream>>>(cp, nexta, leader, S, pg, out);
}